// Round 1
// baseline (515.013 us; speedup 1.0000x reference)
//
#include <hip/hip_runtime.h>
#include <stdint.h>

#define DIM 512
#define ROWS_PER_BLOCK 64
#define N_CHUNKS 32                 // 32 chunks of 16 columns
#define CHUNK_ROW_BF16 520          // 512 data + 8 pad (pad breaks bank conflicts)
#define CHUNK_BF16 (16 * CHUNK_ROW_BF16)
#define CHUNK_BYTES (CHUNK_BF16 * 2)          // 16640
#define CHUNK_WORDS (CHUNK_BYTES / 4)         // 4160
#define WS_BYTES (N_CHUNKS * CHUNK_BYTES)     // 532480

typedef __attribute__((ext_vector_type(8))) short   short8;
typedef __attribute__((ext_vector_type(8))) __bf16  bf16x8;
typedef __attribute__((ext_vector_type(4))) float   f32x4;

static __device__ __forceinline__ unsigned short f2bf(float f) {
  union { float f; uint32_t u; } v; v.f = f;
  uint32_t r = (v.u + 0x7fffu + ((v.u >> 16) & 1u)) >> 16;   // RNE
  return (unsigned short)r;
}
static __device__ __forceinline__ float bf2f(unsigned short s) {
  union { uint32_t u; float f; } v; v.u = ((uint32_t)s) << 16;
  return v.f;
}
static __device__ __forceinline__ bf16x8 as_bf(short8 s) {
  return __builtin_bit_cast(bf16x8, s);
}

// k-permutation within each 32-wide k-block: position q = g*8+j (lane-group g,
// element j) holds actual k-residue (j<4 ? 4g+j : 16+4g+(j-4)). This makes the
// epilogue value delta[r][e] land in the lane's own frag registers.
static __device__ __forceinline__ int kperm(int kk, int q) {
  int g = q >> 3, j = q & 7;
  int r = (j < 4) ? (g * 4 + j) : (16 + g * 4 + (j - 4));
  return kk * 32 + r;
}

// Build bf16 image of R = S - I in d_ws, pre-swizzled+padded as the exact LDS
// layout the main kernel wants: chunk eb -> 16 rows (e_local) x 520 bf16
// (k-permuted positions 0..511, then 8 zero pads).
__global__ void prep_R(const float* __restrict__ S, uint32_t* __restrict__ ws) {
  int idx = blockIdx.x * blockDim.x + threadIdx.x;   // 32-bit word index
  const int total = N_CHUNKS * 16 * (CHUNK_ROW_BF16 / 2);
  if (idx >= total) return;
  const int wpr = CHUNK_ROW_BF16 / 2;                // 260 words per row
  int chunk = idx / (16 * wpr);
  int rem   = idx - chunk * (16 * wpr);
  int e_l   = rem / wpr;
  int wp    = rem - e_l * wpr;
  int pos   = wp * 2;
  uint32_t w = 0;
  if (pos < DIM) {
    int e  = chunk * 16 + e_l;
    int kk = pos >> 5, q = pos & 31;
    int k0 = kperm(kk, q);
    int k1 = kperm(kk, q + 1);
    float v0 = S[k0 * DIM + e] - (k0 == e ? 1.0f : 0.0f);
    float v1 = S[k1 * DIM + e] - (k1 == e ? 1.0f : 0.0f);
    w = (uint32_t)f2bf(v0) | ((uint32_t)f2bf(v1) << 16);
  }
  ws[idx] = w;
}

// Main kernel: out[row] = sumsq_fp32(delta) + delta^T R delta (bf16 MFMA).
// 4 waves/block, 16 rows/wave. Swapped MFMA orientation: C = R_chunk^T * delta^T,
// so C col = lane&15 = this lane's delta row.
__global__ __launch_bounds__(256, 3)
void mahal_main(const float* __restrict__ X, const float* __restrict__ XF,
                const uint32_t* __restrict__ ws, float* __restrict__ out) {
  __shared__ __align__(16) unsigned short sB[CHUNK_BF16];

  const int tid  = threadIdx.x;
  const int lane = tid & 63;
  const int wv   = tid >> 6;
  const int m    = lane & 15;          // delta row within wave / MFMA n-index
  const int g    = lane >> 4;          // lane group
  const int row  = blockIdx.x * ROWS_PER_BLOCK + wv * 16 + m;

  const float* xr = X  + (size_t)row * DIM;
  const float* fr = XF + (size_t)row * DIM;

  // ---- Phase 0: load delta (HBM, once), fp32 sumsq, pack bf16 B-fragments ----
  short8 frag[16];
  float sumsq = 0.f;
#pragma unroll
  for (int kk = 0; kk < 16; ++kk) {
    const float4 a0 = *(const float4*)(xr + kk * 32 + 4 * g);
    const float4 b0 = *(const float4*)(fr + kk * 32 + 4 * g);
    const float4 a1 = *(const float4*)(xr + kk * 32 + 16 + 4 * g);
    const float4 b1 = *(const float4*)(fr + kk * 32 + 16 + 4 * g);
    float d0 = a0.x - b0.x, d1 = a0.y - b0.y, d2 = a0.z - b0.z, d3 = a0.w - b0.w;
    float d4 = a1.x - b1.x, d5 = a1.y - b1.y, d6 = a1.z - b1.z, d7 = a1.w - b1.w;
    sumsq += d0*d0 + d1*d1 + d2*d2 + d3*d3 + d4*d4 + d5*d5 + d6*d6 + d7*d7;
    short8 f;
    f[0] = (short)f2bf(d0); f[1] = (short)f2bf(d1);
    f[2] = (short)f2bf(d2); f[3] = (short)f2bf(d3);
    f[4] = (short)f2bf(d4); f[5] = (short)f2bf(d5);
    f[6] = (short)f2bf(d6); f[7] = (short)f2bf(d7);
    frag[kk] = f;
  }
  // 4 lanes (g=0..3) jointly cover all k of a row
  sumsq += __shfl_xor(sumsq, 16);
  sumsq += __shfl_xor(sumsq, 32);

  // ---- Phase 1: loop over 32 column-chunks of R ----
  float part = 0.f;
#pragma unroll
  for (int eb = 0; eb < N_CHUNKS; ++eb) {
    __syncthreads();                                  // prev chunk reads done
    const uint32_t* src = ws + eb * CHUNK_WORDS;
#pragma unroll
    for (int r = 0; r < 5; ++r) {                     // 1040 x 16B slots
      int idx = r * 256 + tid;
      if (idx < CHUNK_BYTES / 16) {
        __builtin_amdgcn_global_load_lds(
            (const __attribute__((address_space(1))) void*)(src + idx * 4),
            (__attribute__((address_space(3))) void*)(&sB[idx * 8]),
            16, 0, 0);
      }
    }
    __syncthreads();                                  // drains vmcnt

    f32x4 c0 = {0.f, 0.f, 0.f, 0.f}, c1 = {0.f, 0.f, 0.f, 0.f};
#pragma unroll
    for (int kk = 0; kk < 16; kk += 2) {
      short8 ar0 = *(const short8*)(&sB[m * CHUNK_ROW_BF16 + kk * 32 + g * 8]);
      short8 ar1 = *(const short8*)(&sB[m * CHUNK_ROW_BF16 + (kk + 1) * 32 + g * 8]);
      c0 = __builtin_amdgcn_mfma_f32_16x16x32_bf16(as_bf(ar0), as_bf(frag[kk]),     c0, 0, 0, 0);
      c1 = __builtin_amdgcn_mfma_f32_16x16x32_bf16(as_bf(ar1), as_bf(frag[kk + 1]), c1, 0, 0, 0);
    }

    // Epilogue: C row (g*4+i) is e_local; lane's frag holds delta[r][e] at
    // frag[eb>>1][(eb&1)*4 + i] thanks to the k-permutation.
    const short8 f = frag[eb >> 1];
    const int jb = (eb & 1) * 4;
    part += (c0[0] + c1[0]) * bf2f((unsigned short)f[jb + 0]);
    part += (c0[1] + c1[1]) * bf2f((unsigned short)f[jb + 1]);
    part += (c0[2] + c1[2]) * bf2f((unsigned short)f[jb + 2]);
    part += (c0[3] + c1[3]) * bf2f((unsigned short)f[jb + 3]);
  }

  part += __shfl_xor(part, 16);
  part += __shfl_xor(part, 32);
  if (g == 0) out[row] = sumsq + part;
}

// Safety-net (only if ws_size is unexpectedly small): naive fp32, correct.
__global__ void mahal_naive(const float* __restrict__ X, const float* __restrict__ XF,
                            const float* __restrict__ S, float* __restrict__ out, int n) {
  int row = blockIdx.x * blockDim.x + threadIdx.x;
  if (row >= n) return;
  const float* xr = X + (size_t)row * DIM;
  const float* fr = XF + (size_t)row * DIM;
  float acc = 0.f;
  for (int d = 0; d < DIM; ++d) {
    float dd = xr[d] - fr[d];
    float inner = 0.f;
    for (int e = 0; e < DIM; ++e) inner += S[d * DIM + e] * (xr[e] - fr[e]);
    acc += dd * inner;
  }
  out[row] = acc;
}

extern "C" void kernel_launch(void* const* d_in, const int* in_sizes, int n_in,
                              void* d_out, int out_size, void* d_ws, size_t ws_size,
                              hipStream_t stream) {
  const float* X  = (const float*)d_in[0];
  const float* XF = (const float*)d_in[1];
  const float* S  = (const float*)d_in[2];
  float* out = (float*)d_out;
  const int N = in_sizes[0] / DIM;

  if (ws_size < (size_t)WS_BYTES || (N % ROWS_PER_BLOCK) != 0) {
    mahal_naive<<<(N + 63) / 64, 64, 0, stream>>>(X, XF, S, out, N);
    return;
  }

  uint32_t* ws = (uint32_t*)d_ws;
  const int prep_words = N_CHUNKS * 16 * (CHUNK_ROW_BF16 / 2);
  prep_R<<<(prep_words + 255) / 256, 256, 0, stream>>>(S, ws);
  mahal_main<<<N / ROWS_PER_BLOCK, 256, 0, stream>>>(X, XF, ws, out);
}

// Round 2
// 513.697 us; speedup vs baseline: 1.0026x; 1.0026x over previous
//
#include <hip/hip_runtime.h>
#include <stdint.h>

#define DIM 512
#define ROWS_PER_BLOCK 64
#define N_CHUNKS 32                 // 32 chunks of 16 columns
#define CHUNK_ROW_BF16 520          // 512 data + 8 pad (bank-conflict break)
#define CHUNK_BF16 (16 * CHUNK_ROW_BF16)      // 8320 elements
#define CHUNK_BYTES (CHUNK_BF16 * 2)          // 16640
#define CHUNK_WORDS (CHUNK_BYTES / 4)         // 4160
#define WS_BYTES (N_CHUNKS * CHUNK_BYTES)     // 532480

typedef __attribute__((ext_vector_type(8))) short   short8;
typedef __attribute__((ext_vector_type(8))) __bf16  bf16x8;
typedef __attribute__((ext_vector_type(4))) float   f32x4;

static __device__ __forceinline__ unsigned short f2bf(float f) {
  union { float f; uint32_t u; } v; v.f = f;
  uint32_t r = (v.u + 0x7fffu + ((v.u >> 16) & 1u)) >> 16;   // RNE
  return (unsigned short)r;
}
static __device__ __forceinline__ float bf2f(unsigned short s) {
  union { uint32_t u; float f; } v; v.u = ((uint32_t)s) << 16;
  return v.f;
}
static __device__ __forceinline__ bf16x8 as_bf(short8 s) {
  return __builtin_bit_cast(bf16x8, s);
}

// k-permutation within each 32-wide k-block: position q = g*8+j holds actual
// k-residue (j<4 ? 4g+j : 16+4g+(j-4)) so the epilogue value delta[r][e]
// lands in the lane's own frag registers. (Validated correct in round 1.)
static __device__ __forceinline__ int kperm(int kk, int q) {
  int g = q >> 3, j = q & 7;
  int r = (j < 4) ? (g * 4 + j) : (16 + g * 4 + (j - 4));
  return kk * 32 + r;
}

// Build bf16 image of R = S - I in d_ws, pre-swizzled+padded to the exact LDS
// layout: chunk eb -> 16 rows (e_local) x 520 bf16 (k-permuted, then pad).
__global__ void prep_R(const float* __restrict__ S, uint32_t* __restrict__ ws) {
  int idx = blockIdx.x * blockDim.x + threadIdx.x;
  const int total = N_CHUNKS * 16 * (CHUNK_ROW_BF16 / 2);
  if (idx >= total) return;
  const int wpr = CHUNK_ROW_BF16 / 2;                // 260 words per row
  int chunk = idx / (16 * wpr);
  int rem   = idx - chunk * (16 * wpr);
  int e_l   = rem / wpr;
  int wp    = rem - e_l * wpr;
  int pos   = wp * 2;
  uint32_t w = 0;
  if (pos < DIM) {
    int e  = chunk * 16 + e_l;
    int k0 = kperm(pos >> 5, pos & 31);
    int k1 = kperm(pos >> 5, (pos & 31) + 1);
    float v0 = S[k0 * DIM + e] - (k0 == e ? 1.0f : 0.0f);
    float v1 = S[k1 * DIM + e] - (k1 == e ? 1.0f : 0.0f);
    w = (uint32_t)f2bf(v0) | ((uint32_t)f2bf(v1) << 16);
  }
  ws[idx] = w;
}

// Stage one 16.6 KB R-chunk into LDS via async direct-to-LDS, width 16.
static __device__ __forceinline__ void stage_chunk(const uint32_t* __restrict__ ws,
                                                   int eb, unsigned short* dst, int tid) {
  const uint32_t* src = ws + (size_t)eb * CHUNK_WORDS;
#pragma unroll
  for (int r = 0; r < 5; ++r) {                       // 1040 x 16B slots
    int idx = r * 256 + tid;
    if (idx < CHUNK_BYTES / 16) {
      __builtin_amdgcn_global_load_lds(
          (const __attribute__((address_space(1))) void*)(src + idx * 4),
          (__attribute__((address_space(3))) void*)(dst + idx * 8),
          16, 0, 0);
    }
  }
}

// ---- Phase 0: source-level unrolled so frag[KK] is a constant index (SROA) ----
template <int KK>
struct P0 {
  static __device__ __forceinline__ void run(const float* __restrict__ xr,
                                             const float* __restrict__ fr,
                                             int g, short8 (&frag)[16], float& sumsq) {
    const float4 a0 = *(const float4*)(xr + KK * 32 + 4 * g);
    const float4 b0 = *(const float4*)(fr + KK * 32 + 4 * g);
    const float4 a1 = *(const float4*)(xr + KK * 32 + 16 + 4 * g);
    const float4 b1 = *(const float4*)(fr + KK * 32 + 16 + 4 * g);
    float d0 = a0.x - b0.x, d1 = a0.y - b0.y, d2 = a0.z - b0.z, d3 = a0.w - b0.w;
    float d4 = a1.x - b1.x, d5 = a1.y - b1.y, d6 = a1.z - b1.z, d7 = a1.w - b1.w;
    sumsq += d0*d0 + d1*d1 + d2*d2 + d3*d3 + d4*d4 + d5*d5 + d6*d6 + d7*d7;
    short8 f;
    f[0] = (short)f2bf(d0); f[1] = (short)f2bf(d1);
    f[2] = (short)f2bf(d2); f[3] = (short)f2bf(d3);
    f[4] = (short)f2bf(d4); f[5] = (short)f2bf(d5);
    f[6] = (short)f2bf(d6); f[7] = (short)f2bf(d7);
    frag[KK] = f;
    P0<KK + 1>::run(xr, fr, g, frag, sumsq);
  }
};
template <>
struct P0<16> {
  static __device__ __forceinline__ void run(const float*, const float*, int,
                                             short8 (&)[16], float&) {}
};

// ---- K-loop: constant frag indices ----
template <int KK>
struct KLoop {
  static __device__ __forceinline__ void run(const unsigned short* __restrict__ base,
                                             const short8 (&frag)[16], f32x4& c0, f32x4& c1) {
    short8 ar0 = *(const short8*)(base + KK * 32);
    short8 ar1 = *(const short8*)(base + (KK + 1) * 32);
    c0 = __builtin_amdgcn_mfma_f32_16x16x32_bf16(as_bf(ar0), as_bf(frag[KK]),     c0, 0, 0, 0);
    c1 = __builtin_amdgcn_mfma_f32_16x16x32_bf16(as_bf(ar1), as_bf(frag[KK + 1]), c1, 0, 0, 0);
    KLoop<KK + 2>::run(base, frag, c0, c1);
  }
};
template <>
struct KLoop<16> {
  static __device__ __forceinline__ void run(const unsigned short*, const short8 (&)[16],
                                             f32x4&, f32x4&) {}
};

// ---- Chunk loop, double-buffered: stage EB+1 while computing EB ----
template <int EB>
struct ChunkLoop {
  static __device__ __forceinline__ void run(const uint32_t* __restrict__ ws,
                                             unsigned short* sA0, unsigned short* sA1,
                                             int tid, int m, int g,
                                             const short8 (&frag)[16], float& part) {
    unsigned short* cur = (EB & 1) ? sA1 : sA0;
    unsigned short* nxt = (EB & 1) ? sA0 : sA1;
    if (EB + 1 < N_CHUNKS) stage_chunk(ws, EB + 1, nxt, tid);

    f32x4 c0 = {0.f, 0.f, 0.f, 0.f}, c1 = {0.f, 0.f, 0.f, 0.f};
    KLoop<0>::run(cur + m * CHUNK_ROW_BF16 + g * 8, frag, c0, c1);

    // Epilogue: C row (g*4+i) = e_local; delta[r][e] sits at frag[EB>>1][(EB&1)*4+i].
    const short8 f = frag[EB >> 1];
    constexpr int jb = (EB & 1) * 4;
    part += (c0[0] + c1[0]) * bf2f((unsigned short)f[jb + 0]);
    part += (c0[1] + c1[1]) * bf2f((unsigned short)f[jb + 1]);
    part += (c0[2] + c1[2]) * bf2f((unsigned short)f[jb + 2]);
    part += (c0[3] + c1[3]) * bf2f((unsigned short)f[jb + 3]);

    __syncthreads();   // drains vmcnt: chunk EB+1 staged; cur free for re-stage
    ChunkLoop<EB + 1>::run(ws, sA0, sA1, tid, m, g, frag, part);
  }
};
template <>
struct ChunkLoop<N_CHUNKS> {
  static __device__ __forceinline__ void run(const uint32_t*, unsigned short*,
                                             unsigned short*, int, int, int,
                                             const short8 (&)[16], float&) {}
};

// out[row] = fp32 sumsq(delta) + delta^T R delta (bf16 MFMA, C = R_chunk^T delta^T).
__global__ __launch_bounds__(256, 3)
void mahal_main(const float* __restrict__ X, const float* __restrict__ XF,
                const uint32_t* __restrict__ ws, float* __restrict__ out) {
  __shared__ __align__(16) unsigned short sA[2][CHUNK_BF16];   // 33280 B

  const int tid  = threadIdx.x;
  const int lane = tid & 63;
  const int wv   = tid >> 6;
  const int m    = lane & 15;          // delta row within wave
  const int g    = lane >> 4;          // lane group
  const int row  = blockIdx.x * ROWS_PER_BLOCK + wv * 16 + m;

  const float* xr = X  + (size_t)row * DIM;
  const float* fr = XF + (size_t)row * DIM;

  // Kick off chunk-0 staging first so it overlaps phase-0 HBM reads.
  stage_chunk(ws, 0, sA[0], tid);

  short8 frag[16];
  float sumsq = 0.f;
  P0<0>::run(xr, fr, g, frag, sumsq);
  sumsq += __shfl_xor(sumsq, 16);
  sumsq += __shfl_xor(sumsq, 32);

  __syncthreads();                     // chunk 0 visible

  float part = 0.f;
  ChunkLoop<0>::run(ws, sA[0], sA[1], tid, m, g, frag, part);

  part += __shfl_xor(part, 16);
  part += __shfl_xor(part, 32);
  if (g == 0) out[row] = sumsq + part;
}

// Safety-net (only if ws_size is unexpectedly small): naive fp32, correct.
__global__ void mahal_naive(const float* __restrict__ X, const float* __restrict__ XF,
                            const float* __restrict__ S, float* __restrict__ out, int n) {
  int row = blockIdx.x * blockDim.x + threadIdx.x;
  if (row >= n) return;
  const float* xr = X + (size_t)row * DIM;
  const float* fr = XF + (size_t)row * DIM;
  float acc = 0.f;
  for (int d = 0; d < DIM; ++d) {
    float dd = xr[d] - fr[d];
    float inner = 0.f;
    for (int e = 0; e < DIM; ++e) inner += S[d * DIM + e] * (xr[e] - fr[e]);
    acc += dd * inner;
  }
  out[row] = acc;
}

extern "C" void kernel_launch(void* const* d_in, const int* in_sizes, int n_in,
                              void* d_out, int out_size, void* d_ws, size_t ws_size,
                              hipStream_t stream) {
  const float* X  = (const float*)d_in[0];
  const float* XF = (const float*)d_in[1];
  const float* S  = (const float*)d_in[2];
  float* out = (float*)d_out;
  const int N = in_sizes[0] / DIM;

  if (ws_size < (size_t)WS_BYTES || (N % ROWS_PER_BLOCK) != 0) {
    mahal_naive<<<(N + 63) / 64, 64, 0, stream>>>(X, XF, S, out, N);
    return;
  }

  uint32_t* ws = (uint32_t*)d_ws;
  const int prep_words = N_CHUNKS * 16 * (CHUNK_ROW_BF16 / 2);
  prep_R<<<(prep_words + 255) / 256, 256, 0, stream>>>(S, ws);
  mahal_main<<<N / ROWS_PER_BLOCK, 256, 0, stream>>>(X, XF, ws, out);
}

// Round 3
// 413.765 us; speedup vs baseline: 1.2447x; 1.2415x over previous
//
#include <hip/hip_runtime.h>
#include <stdint.h>

#define DIM 512
#define ROWS_PER_BLOCK 64
#define N_CHUNKS 32                 // 32 chunks of 16 columns
#define CHUNK_ROW_BF16 520          // 512 data + 8 pad (bank-conflict break)
#define CHUNK_BF16 (16 * CHUNK_ROW_BF16)      // 8320 elements
#define CHUNK_BYTES (CHUNK_BF16 * 2)          // 16640
#define CHUNK_WORDS (CHUNK_BYTES / 4)         // 4160
#define WS_BYTES (N_CHUNKS * CHUNK_BYTES)     // 532480

typedef __attribute__((ext_vector_type(8))) short   short8;
typedef __attribute__((ext_vector_type(8))) __bf16  bf16x8;
typedef __attribute__((ext_vector_type(4))) float   f32x4;

static __device__ __forceinline__ unsigned short f2bf(float f) {
  union { float f; uint32_t u; } v; v.f = f;
  uint32_t r = (v.u + 0x7fffu + ((v.u >> 16) & 1u)) >> 16;   // RNE
  return (unsigned short)r;
}
static __device__ __forceinline__ float bf2f(unsigned short s) {
  union { uint32_t u; float f; } v; v.u = ((uint32_t)s) << 16;
  return v.f;
}
static __device__ __forceinline__ bf16x8 as_bf(short8 s) {
  return __builtin_bit_cast(bf16x8, s);
}

// k-permutation within each 32-wide k-block: position q = g*8+j holds actual
// k-residue (j<4 ? 4g+j : 16+4g+(j-4)) so the epilogue value delta[r][e]
// lands in the lane's own frag registers. (Validated correct in rounds 1-2.)
static __device__ __forceinline__ int kperm(int kk, int q) {
  int g = q >> 3, j = q & 7;
  int r = (j < 4) ? (g * 4 + j) : (16 + g * 4 + (j - 4));
  return kk * 32 + r;
}

// Build bf16 image of R = S - I in d_ws, pre-swizzled+padded to the exact LDS
// layout: chunk eb -> 16 rows (e_local) x 520 bf16 (k-permuted, then pad).
__global__ void prep_R(const float* __restrict__ S, uint32_t* __restrict__ ws) {
  int idx = blockIdx.x * blockDim.x + threadIdx.x;
  const int total = N_CHUNKS * 16 * (CHUNK_ROW_BF16 / 2);
  if (idx >= total) return;
  const int wpr = CHUNK_ROW_BF16 / 2;                // 260 words per row
  int chunk = idx / (16 * wpr);
  int rem   = idx - chunk * (16 * wpr);
  int e_l   = rem / wpr;
  int wp    = rem - e_l * wpr;
  int pos   = wp * 2;
  uint32_t w = 0;
  if (pos < DIM) {
    int e  = chunk * 16 + e_l;
    int k0 = kperm(pos >> 5, pos & 31);
    int k1 = kperm(pos >> 5, (pos & 31) + 1);
    float v0 = S[k0 * DIM + e] - (k0 == e ? 1.0f : 0.0f);
    float v1 = S[k1 * DIM + e] - (k1 == e ? 1.0f : 0.0f);
    w = (uint32_t)f2bf(v0) | ((uint32_t)f2bf(v1) << 16);
  }
  ws[idx] = w;
}

// Stage one 16.6 KB R-chunk into LDS via async direct-to-LDS, width 16.
static __device__ __forceinline__ void stage_chunk(const uint32_t* __restrict__ ws,
                                                   int eb, unsigned short* dst, int tid) {
  const uint32_t* src = ws + (size_t)eb * CHUNK_WORDS;
#pragma unroll
  for (int r = 0; r < 5; ++r) {                       // 1040 x 16B slots
    int idx = r * 256 + tid;
    if (idx < CHUNK_BYTES / 16) {
      __builtin_amdgcn_global_load_lds(
          (const __attribute__((address_space(1))) void*)(src + idx * 4),
          (__attribute__((address_space(3))) void*)(dst + idx * 8),
          16, 0, 0);
    }
  }
}

// ---- Phase 0: source-level unrolled so frag[KK] is a constant index ----
template <int KK>
struct P0 {
  static __device__ __forceinline__ void run(const float* __restrict__ xr,
                                             const float* __restrict__ fr,
                                             int g, short8 (&frag)[16], float& sumsq) {
    const float4 a0 = *(const float4*)(xr + KK * 32 + 4 * g);
    const float4 b0 = *(const float4*)(fr + KK * 32 + 4 * g);
    const float4 a1 = *(const float4*)(xr + KK * 32 + 16 + 4 * g);
    const float4 b1 = *(const float4*)(fr + KK * 32 + 16 + 4 * g);
    float d0 = a0.x - b0.x, d1 = a0.y - b0.y, d2 = a0.z - b0.z, d3 = a0.w - b0.w;
    float d4 = a1.x - b1.x, d5 = a1.y - b1.y, d6 = a1.z - b1.z, d7 = a1.w - b1.w;
    sumsq += d0*d0 + d1*d1 + d2*d2 + d3*d3 + d4*d4 + d5*d5 + d6*d6 + d7*d7;
    short8 f;
    f[0] = (short)f2bf(d0); f[1] = (short)f2bf(d1);
    f[2] = (short)f2bf(d2); f[3] = (short)f2bf(d3);
    f[4] = (short)f2bf(d4); f[5] = (short)f2bf(d5);
    f[6] = (short)f2bf(d6); f[7] = (short)f2bf(d7);
    frag[KK] = f;
    P0<KK + 1>::run(xr, fr, g, frag, sumsq);
  }
};
template <>
struct P0<16> {
  static __device__ __forceinline__ void run(const float*, const float*, int,
                                             short8 (&)[16], float&) {}
};

// ---- K-loop: constant frag indices ----
template <int KK>
struct KLoop {
  static __device__ __forceinline__ void run(const unsigned short* __restrict__ base,
                                             const short8 (&frag)[16], f32x4& c0, f32x4& c1) {
    short8 ar0 = *(const short8*)(base + KK * 32);
    short8 ar1 = *(const short8*)(base + (KK + 1) * 32);
    c0 = __builtin_amdgcn_mfma_f32_16x16x32_bf16(as_bf(ar0), as_bf(frag[KK]),     c0, 0, 0, 0);
    c1 = __builtin_amdgcn_mfma_f32_16x16x32_bf16(as_bf(ar1), as_bf(frag[KK + 1]), c1, 0, 0, 0);
    KLoop<KK + 2>::run(base, frag, c0, c1);
  }
};
template <>
struct KLoop<16> {
  static __device__ __forceinline__ void run(const unsigned short*, const short8 (&)[16],
                                             f32x4&, f32x4&) {}
};

// ---- Chunk loop, double-buffered: stage EB+1 while computing EB ----
template <int EB>
struct ChunkLoop {
  static __device__ __forceinline__ void run(const uint32_t* __restrict__ ws,
                                             unsigned short* sA0, unsigned short* sA1,
                                             int tid, int m, int g,
                                             const short8 (&frag)[16], float& part) {
    unsigned short* cur = (EB & 1) ? sA1 : sA0;
    unsigned short* nxt = (EB & 1) ? sA0 : sA1;
    if (EB + 1 < N_CHUNKS) stage_chunk(ws, EB + 1, nxt, tid);

    f32x4 c0 = {0.f, 0.f, 0.f, 0.f}, c1 = {0.f, 0.f, 0.f, 0.f};
    KLoop<0>::run(cur + m * CHUNK_ROW_BF16 + g * 8, frag, c0, c1);

    // Epilogue: C row (g*4+i) = e_local; delta[r][e] sits at frag[EB>>1][(EB&1)*4+i].
    const short8 f = frag[EB >> 1];
    constexpr int jb = (EB & 1) * 4;
    part += (c0[0] + c1[0]) * bf2f((unsigned short)f[jb + 0]);
    part += (c0[1] + c1[1]) * bf2f((unsigned short)f[jb + 1]);
    part += (c0[2] + c1[2]) * bf2f((unsigned short)f[jb + 2]);
    part += (c0[3] + c1[3]) * bf2f((unsigned short)f[jb + 3]);

    __syncthreads();   // drains vmcnt: chunk EB+1 staged; cur free for re-stage
    ChunkLoop<EB + 1>::run(ws, sA0, sA1, tid, m, g, frag, part);
  }
};
template <>
struct ChunkLoop<N_CHUNKS> {
  static __device__ __forceinline__ void run(const uint32_t*, unsigned short*,
                                             unsigned short*, int, int, int,
                                             const short8 (&)[16], float&) {}
};

// out[row] = fp32 sumsq(delta) + delta^T R delta (bf16 MFMA, C = R_chunk^T delta^T).
// launch_bounds (256,2): 256 unified VGPRs/wave so frag[16] (64 regs) stays
// register-resident. (256,3) capped at ~170 -> 84 arch VGPRs -> 340 MB of
// scratch spill traffic per launch (rounds 1-2 evidence).
__global__ __launch_bounds__(256, 2)
void mahal_main(const float* __restrict__ X, const float* __restrict__ XF,
                const uint32_t* __restrict__ ws, float* __restrict__ out) {
  __shared__ __align__(16) unsigned short sA[2][CHUNK_BF16];   // 33280 B

  const int tid  = threadIdx.x;
  const int lane = tid & 63;
  const int wv   = tid >> 6;
  const int m    = lane & 15;          // delta row within wave
  const int g    = lane >> 4;          // lane group
  const int row  = blockIdx.x * ROWS_PER_BLOCK + wv * 16 + m;

  const float* xr = X  + (size_t)row * DIM;
  const float* fr = XF + (size_t)row * DIM;

  // Kick off chunk-0 staging first so it overlaps phase-0 HBM reads.
  stage_chunk(ws, 0, sA[0], tid);

  short8 frag[16];
  float sumsq = 0.f;
  P0<0>::run(xr, fr, g, frag, sumsq);
  sumsq += __shfl_xor(sumsq, 16);
  sumsq += __shfl_xor(sumsq, 32);

  __syncthreads();                     // chunk 0 visible

  float part = 0.f;
  ChunkLoop<0>::run(ws, sA[0], sA[1], tid, m, g, frag, part);

  part += __shfl_xor(part, 16);
  part += __shfl_xor(part, 32);
  if (g == 0) out[row] = sumsq + part;
}

// Safety-net (only if ws_size is unexpectedly small): naive fp32, correct.
__global__ void mahal_naive(const float* __restrict__ X, const float* __restrict__ XF,
                            const float* __restrict__ S, float* __restrict__ out, int n) {
  int row = blockIdx.x * blockDim.x + threadIdx.x;
  if (row >= n) return;
  const float* xr = X + (size_t)row * DIM;
  const float* fr = XF + (size_t)row * DIM;
  float acc = 0.f;
  for (int d = 0; d < DIM; ++d) {
    float dd = xr[d] - fr[d];
    float inner = 0.f;
    for (int e = 0; e < DIM; ++e) inner += S[d * DIM + e] * (xr[e] - fr[e]);
    acc += dd * inner;
  }
  out[row] = acc;
}

extern "C" void kernel_launch(void* const* d_in, const int* in_sizes, int n_in,
                              void* d_out, int out_size, void* d_ws, size_t ws_size,
                              hipStream_t stream) {
  const float* X  = (const float*)d_in[0];
  const float* XF = (const float*)d_in[1];
  const float* S  = (const float*)d_in[2];
  float* out = (float*)d_out;
  const int N = in_sizes[0] / DIM;

  if (ws_size < (size_t)WS_BYTES || (N % ROWS_PER_BLOCK) != 0) {
    mahal_naive<<<(N + 63) / 64, 64, 0, stream>>>(X, XF, S, out, N);
    return;
  }

  uint32_t* ws = (uint32_t*)d_ws;
  const int prep_words = N_CHUNKS * 16 * (CHUNK_ROW_BF16 / 2);
  prep_R<<<(prep_words + 255) / 256, 256, 0, stream>>>(S, ws);
  mahal_main<<<N / ROWS_PER_BLOCK, 256, 0, stream>>>(X, XF, ws, out);
}

// Round 4
// 302.848 us; speedup vs baseline: 1.7006x; 1.3662x over previous
//
#include <hip/hip_runtime.h>
#include <stdint.h>

#define DIM 512
#define ROWS_PER_BLOCK 64
#define N_CHUNKS 32                      // 32 chunks of 16 e-columns
#define CHUNK_BYTES 8192                 // 16 rows x 512 fp8 (atom-rotated, no pad)
#define WS_BYTES (N_CHUNKS * CHUNK_BYTES)   // 262144

typedef __attribute__((ext_vector_type(4))) float f32x4;
typedef __attribute__((ext_vector_type(2))) float f32x2;
typedef __attribute__((ext_vector_type(4))) int   i32x4;

// k-permutation (validated rounds 1-3): position q = g*8+j within 32-k block kk
// holds k = 32*kk + (j<4 ? 4g+j : 16+4g+(j-4)). Any A/B-consistent bijection is
// mathematically valid; this one puts epilogue value delta[r][e] in-lane:
// e = 16*eb + 4g + i  <->  frag[eb>>1], byte (eb&1)*4 + i.
static __device__ __forceinline__ int kperm(int kk, int q) {
  int g = q >> 3, j = q & 7;
  int r = (j < 4) ? (g * 4 + j) : (16 + g * 4 + (j - 4));
  return kk * 32 + r;
}

// Build fp8 image of 64*(S - I), pre-swizzled: chunk -> 16 rows (e_l) x 512 B.
// Within a row, 16B atom (P,g) [atom index 4P+g] is stored at physical slot
// ((4P+g)+e_l)&31 — per-row rotation makes the K-loop's b128 reads spread
// evenly over all 32 banks (8/bank minimum for b128, no hot bank).
__global__ void prep_R(const float* __restrict__ S, uint32_t* __restrict__ ws) {
  int idx = blockIdx.x * blockDim.x + threadIdx.x;   // word index
  if (idx >= WS_BYTES / 4) return;
  int b     = idx * 4;
  int chunk = b >> 13;
  int e_l   = (b >> 9) & 15;
  int inrow = b & 511;
  int slot  = inrow >> 4;
  int bia   = inrow & 15;                // byte-in-atom base (0,4,8,12)
  int la    = (slot - e_l) & 31;         // logical atom = 4P+g
  int P = la >> 2, g = la & 3;
  int e = chunk * 16 + e_l;
  float v[4];
#pragma unroll
  for (int t = 0; t < 4; ++t) {
    int bb = bia + t;                    // byte in atom 0..15
    int j  = bb & 7;
    int kk = 2 * P + (bb >> 3);
    int k  = kperm(kk, g * 8 + j);
    v[t] = 64.0f * (S[k * DIM + e] - (k == e ? 1.0f : 0.0f));   // x64: e4m3 range
  }
  int w = __builtin_amdgcn_cvt_pk_fp8_f32(v[0], v[1], 0, false);
  w     = __builtin_amdgcn_cvt_pk_fp8_f32(v[2], v[3], w, true);
  ws[idx] = (uint32_t)w;
}

// Stage one 8 KB R-chunk into LDS (async direct-to-LDS, width 16, linear).
static __device__ __forceinline__ void stage_chunk(const uint32_t* __restrict__ ws,
                                                   int eb, char* dst, int tid) {
  const uint32_t* src = ws + (size_t)eb * (CHUNK_BYTES / 4);
#pragma unroll
  for (int r = 0; r < 2; ++r) {                      // 512 x 16B slots
    int idx = r * 256 + tid;
    __builtin_amdgcn_global_load_lds(
        (const __attribute__((address_space(1))) void*)(src + idx * 4),
        (__attribute__((address_space(3))) void*)(dst + idx * 16),
        16, 0, 0);
  }
}

// ---- Phase 0 (template-unrolled, constant frag indices) ----
template <int KK>
struct P0 {
  static __device__ __forceinline__ void run(const float* __restrict__ xr,
                                             const float* __restrict__ fr,
                                             int g, long long (&fragL)[16], float& sumsq) {
    const float4 a0 = *(const float4*)(xr + KK * 32 + 4 * g);
    const float4 b0 = *(const float4*)(fr + KK * 32 + 4 * g);
    const float4 a1 = *(const float4*)(xr + KK * 32 + 16 + 4 * g);
    const float4 b1 = *(const float4*)(fr + KK * 32 + 16 + 4 * g);
    float d0 = a0.x - b0.x, d1 = a0.y - b0.y, d2 = a0.z - b0.z, d3 = a0.w - b0.w;
    float d4 = a1.x - b1.x, d5 = a1.y - b1.y, d6 = a1.z - b1.z, d7 = a1.w - b1.w;
    sumsq += d0*d0 + d1*d1 + d2*d2 + d3*d3 + d4*d4 + d5*d5 + d6*d6 + d7*d7;
    int lo = __builtin_amdgcn_cvt_pk_fp8_f32(d0, d1, 0, false);
    lo     = __builtin_amdgcn_cvt_pk_fp8_f32(d2, d3, lo, true);
    int hi = __builtin_amdgcn_cvt_pk_fp8_f32(d4, d5, 0, false);
    hi     = __builtin_amdgcn_cvt_pk_fp8_f32(d6, d7, hi, true);
    fragL[KK] = (long long)(((unsigned long long)(unsigned)hi << 32) | (unsigned)lo);
    P0<KK + 1>::run(xr, fr, g, fragL, sumsq);
  }
};
template <>
struct P0<16> {
  static __device__ __forceinline__ void run(const float*, const float*, int,
                                             long long (&)[16], float&) {}
};

// ---- K-loop over 8 atom-steps; each b128 feeds two fp8 MFMAs ----
template <int P>
struct KLoop {
  static __device__ __forceinline__ void run(const char* __restrict__ rowbase,
                                             int g, int m,
                                             const long long (&fragL)[16],
                                             f32x4& c0, f32x4& c1) {
    int off = ((4 * P + g + m) & 31) * 16;           // rotated atom slot
    i32x4 a = *(const i32x4*)(rowbase + off);
    long long A0 = (long long)(((unsigned long long)(unsigned)a[1] << 32) | (unsigned)a[0]);
    long long A1 = (long long)(((unsigned long long)(unsigned)a[3] << 32) | (unsigned)a[2]);
    c0 = __builtin_amdgcn_mfma_f32_16x16x32_fp8_fp8(A0, fragL[2 * P],     c0, 0, 0, 0);
    c1 = __builtin_amdgcn_mfma_f32_16x16x32_fp8_fp8(A1, fragL[2 * P + 1], c1, 0, 0, 0);
    KLoop<P + 1>::run(rowbase, g, m, fragL, c0, c1);
  }
};
template <>
struct KLoop<8> {
  static __device__ __forceinline__ void run(const char*, int, int,
                                             const long long (&)[16], f32x4&, f32x4&) {}
};

// ---- Chunk loop, double-buffered ----
template <int EB>
struct ChunkLoop {
  static __device__ __forceinline__ void run(const uint32_t* __restrict__ ws,
                                             char* sA0, char* sA1,
                                             int tid, int m, int g,
                                             const long long (&fragL)[16], float& part) {
    char* cur = (EB & 1) ? sA1 : sA0;
    char* nxt = (EB & 1) ? sA0 : sA1;
    if (EB + 1 < N_CHUNKS) stage_chunk(ws, EB + 1, nxt, tid);

    f32x4 c0 = {0.f, 0.f, 0.f, 0.f}, c1 = {0.f, 0.f, 0.f, 0.f};
    KLoop<0>::run(cur + m * 512, g, m, fragL, c0, c1);

    // Epilogue: C row (g*4+i)=e_local; delta[r][e] is byte (EB&1)*4+i of fragL[EB>>1].
    constexpr int kk = EB >> 1;
    int src = (int)(fragL[kk] >> ((EB & 1) * 32));
    f32x2 f01 = __builtin_amdgcn_cvt_pk_f32_fp8(src, false);
    f32x2 f23 = __builtin_amdgcn_cvt_pk_f32_fp8(src, true);
    part += (c0[0] + c1[0]) * f01[0] + (c0[1] + c1[1]) * f01[1]
          + (c0[2] + c1[2]) * f23[0] + (c0[3] + c1[3]) * f23[1];

    __syncthreads();   // drains vmcnt: chunk EB+1 staged; cur free for re-stage
    ChunkLoop<EB + 1>::run(ws, sA0, sA1, tid, m, g, fragL, part);
  }
};
template <>
struct ChunkLoop<N_CHUNKS> {
  static __device__ __forceinline__ void run(const uint32_t*, char*, char*, int, int, int,
                                             const long long (&)[16], float&) {}
};

// out[row] = fp32 sumsq(delta) + (1/64) * delta^T (64R) delta  via fp8 MFMA.
// fp8 frag = 32 VGPRs (vs 64 bf16) — fits the allocator's 50:50 arch/acc split
// at launch_bounds(256,2) (rounds 2-3: 128 arch regs), killing the scratch spill.
__global__ __launch_bounds__(256, 2)
void mahal_main(const float* __restrict__ X, const float* __restrict__ XF,
                const uint32_t* __restrict__ ws, float* __restrict__ out) {
  __shared__ __align__(16) char sA[2][CHUNK_BYTES];   // 16 KB

  const int tid  = threadIdx.x;
  const int lane = tid & 63;
  const int wv   = tid >> 6;
  const int m    = lane & 15;          // delta row within wave
  const int g    = lane >> 4;          // lane group
  const int row  = blockIdx.x * ROWS_PER_BLOCK + wv * 16 + m;

  const float* xr = X  + (size_t)row * DIM;
  const float* fr = XF + (size_t)row * DIM;

  stage_chunk(ws, 0, sA[0], tid);      // overlap chunk-0 staging with phase 0

  long long fragL[16];
  float sumsq = 0.f;
  P0<0>::run(xr, fr, g, fragL, sumsq);
  sumsq += __shfl_xor(sumsq, 16);
  sumsq += __shfl_xor(sumsq, 32);

  __syncthreads();                     // chunk 0 visible

  float part = 0.f;
  ChunkLoop<0>::run(ws, sA[0], sA[1], tid, m, g, fragL, part);

  part += __shfl_xor(part, 16);
  part += __shfl_xor(part, 32);
  if (g == 0) out[row] = sumsq + part * 0.015625f;   // 1/64 undoes R scaling
}

// Safety-net (only if ws_size is unexpectedly small): naive fp32, correct.
__global__ void mahal_naive(const float* __restrict__ X, const float* __restrict__ XF,
                            const float* __restrict__ S, float* __restrict__ out, int n) {
  int row = blockIdx.x * blockDim.x + threadIdx.x;
  if (row >= n) return;
  const float* xr = X + (size_t)row * DIM;
  const float* fr = XF + (size_t)row * DIM;
  float acc = 0.f;
  for (int d = 0; d < DIM; ++d) {
    float dd = xr[d] - fr[d];
    float inner = 0.f;
    for (int e = 0; e < DIM; ++e) inner += S[d * DIM + e] * (xr[e] - fr[e]);
    acc += dd * inner;
  }
  out[row] = acc;
}

extern "C" void kernel_launch(void* const* d_in, const int* in_sizes, int n_in,
                              void* d_out, int out_size, void* d_ws, size_t ws_size,
                              hipStream_t stream) {
  const float* X  = (const float*)d_in[0];
  const float* XF = (const float*)d_in[1];
  const float* S  = (const float*)d_in[2];
  float* out = (float*)d_out;
  const int N = in_sizes[0] / DIM;

  if (ws_size < (size_t)WS_BYTES || (N % ROWS_PER_BLOCK) != 0) {
    mahal_naive<<<(N + 63) / 64, 64, 0, stream>>>(X, XF, S, out, N);
    return;
  }

  uint32_t* ws = (uint32_t*)d_ws;
  prep_R<<<(WS_BYTES / 4 + 255) / 256, 256, 0, stream>>>(S, ws);
  mahal_main<<<N / ROWS_PER_BLOCK, 256, 0, stream>>>(X, XF, ws, out);
}